// Round 1
// baseline (173.035 us; speedup 1.0000x reference)
//
#include <hip/hip_runtime.h>
#include <hip/hip_bf16.h>
#include <stdint.h>

typedef short short8 __attribute__((ext_vector_type(8)));
typedef float f32x4 __attribute__((ext_vector_type(4)));

// Problem constants
constexpr int SEQ   = 2048;   // T
constexpr int DM    = 1024;   // model dim
constexpr int NHEAD = 16;
constexpr int HD    = 64;     // head dim
constexpr int LDQ   = 1152;   // QKV row stride: 1024 Q | 64 K | 64 V
constexpr int BATCH = 2;

__device__ __forceinline__ unsigned short f2bf(float f) {
    union { float f; uint32_t u; } v; v.f = f;
    uint32_t u = v.u;
    uint32_t r = (u + 0x7fffu + ((u >> 16) & 1u)) >> 16;
    return (unsigned short)r;
}

// async global->LDS, 16B per lane. LDS dest = wave-uniform base + lane*16.
typedef __attribute__((address_space(1))) const void gvoid_t;
typedef __attribute__((address_space(3))) void lvoid_t;
__device__ __forceinline__ void gload16(const void* g, void* l) {
    __builtin_amdgcn_global_load_lds((gvoid_t*)g, (lvoid_t*)l, 16, 0, 0);
}

// ---------------- cast x (fp32 -> bf16), vectorized ----------------
__global__ __launch_bounds__(256) void cast_x_kernel(
        const float* __restrict__ x, unsigned short* __restrict__ xb, int n) {
    int i = (blockIdx.x * 256 + threadIdx.x) * 4;
    if (i >= n) return;
    const float4 v = *(const float4*)(x + i);
    ushort4 o;
    o.x = f2bf(v.x); o.y = f2bf(v.y); o.z = f2bf(v.z); o.w = f2bf(v.w);
    *(ushort4*)(xb + i) = o;
}

// ---- fused weight prep: cast+transpose Wq,Wk,Wv,Wo in one launch ----
__global__ __launch_bounds__(256) void prep_w_kernel(
        const float* __restrict__ Wq, const float* __restrict__ Wk,
        const float* __restrict__ Wv, const float* __restrict__ Wo,
        unsigned short* __restrict__ wtq, unsigned short* __restrict__ wot) {
    __shared__ unsigned short tile[32][33];
    int z = blockIdx.z;
    const float* W; unsigned short* Wt; int C;
    if (z == 0)      { W = Wq; Wt = wtq;                              C = DM; }
    else if (z == 1) { W = Wk; Wt = wtq + (size_t)DM * DM;            C = HD; }
    else if (z == 2) { W = Wv; Wt = wtq + (size_t)(DM + HD) * DM;     C = HD; }
    else             { W = Wo; Wt = wot;                              C = DM; }
    int c0 = blockIdx.x * 32, r0 = blockIdx.y * 32;
    if (c0 >= C) return;
    int tx = threadIdx.x & 31, ty = threadIdx.x >> 5;  // ty 0..7
    for (int i = ty; i < 32; i += 8)
        tile[i][tx] = f2bf(W[(size_t)(r0 + i) * C + (c0 + tx)]);
    __syncthreads();
    for (int i = ty; i < 32; i += 8)
        Wt[(size_t)(c0 + i) * DM + (r0 + tx)] = tile[tx][i];
}

// --------- GEMM (m97 structure): C[M,N] = A[M,K](bf16) @ Bt[N,K]^T ---------
// 128x128 tile, BK=64, double-buffered LDS (64 KB), global_load_lds width-16
// staging with (row&7) xor chunk swizzle pre-applied on the GLOBAL source
// (linear LDS dest) and the matching xor applied on the ds_read side.
// 4 waves, each owns a 64x64 quadrant: acc[4][4] of 16x16, 32 MFMA per
// K-step per wave vs 16 ds_read_b128 -> matrix-pipe ~balanced with LDS.
// 1D grid with bijective XCD-aware remap: block g -> xcd=g&7 owns a
// contiguous strip of row-tiles so A-panels are reused from one XCD L2.
// rows_per_xcd = grid/(8*ncols) must be integral (QKV: 288/(8*9)=4,
// out-proj: 256/(8*8)=4).
__global__ __launch_bounds__(256) void gemm128_kernel(
        const unsigned short* __restrict__ A,
        const unsigned short* __restrict__ Bt,
        void* __restrict__ Cout,
        unsigned short* __restrict__ VtOut,
        int M, int N, int K, int out_bf16, int ncols) {
    __shared__ unsigned short ldsA[2][128 * 64];
    __shared__ unsigned short ldsB[2][128 * 64];
    int lane = threadIdx.x & 63, wave = threadIdx.x >> 6;
    int ln = lane & 15, quad = lane >> 4;
    int wm = wave >> 1, wn = wave & 1;

    // XCD-aware block remap (bijective: gridDim.x % 8 == 0)
    int g = blockIdx.x;
    int xcd = g & 7, idx = g >> 3;
    int rows_per_xcd = (int)(gridDim.x >> 3) / ncols;
    int row = xcd * rows_per_xcd + idx / ncols;
    int col = idx % ncols;
    int m0 = row * 128, n0 = col * 128;

    int t = threadIdx.x;
    int trow = t >> 3, tcb = t & 7;          // 32 rows x 8 chunks per batch
    int gcb = tcb ^ (trow & 7);              // pre-swizzled global chunk
    const unsigned short* gA = A + (size_t)(m0 + trow) * K + gcb * 8;
    const unsigned short* gB = Bt + (size_t)(n0 + trow) * K + gcb * 8;
    int dst = t * 8;                          // shorts; batch rr adds 2048

    auto stage = [&](int k0, int buf) {
#pragma unroll
        for (int rr = 0; rr < 4; ++rr) {
            gload16(gA + (size_t)rr * 32 * K + k0, &ldsA[buf][dst + rr * 2048]);
            gload16(gB + (size_t)rr * 32 * K + k0, &ldsB[buf][dst + rr * 2048]);
        }
    };

    f32x4 acc[4][4];
#pragma unroll
    for (int i = 0; i < 4; ++i)
#pragma unroll
        for (int j = 0; j < 4; ++j) acc[i][j] = f32x4{0, 0, 0, 0};

    stage(0, 0);
    int niter = K >> 6;
    for (int it = 0; it < niter; ++it) {
        __syncthreads();                       // drains vmcnt: buf(it&1) ready
        if (it + 1 < niter) stage((it + 1) << 6, (it + 1) & 1);
        const unsigned short* La = ldsA[it & 1];
        const unsigned short* Lb = ldsB[it & 1];
#pragma unroll
        for (int hh = 0; hh < 2; ++hh) {
            int kc = hh * 4 + quad;
            short8 aF[4], bF[4];
#pragma unroll
            for (int mt = 0; mt < 4; ++mt)
                aF[mt] = *(const short8*)&La[(wm * 64 + mt * 16 + ln) * 64 +
                                             ((kc ^ (ln & 7)) * 8)];
#pragma unroll
            for (int nt = 0; nt < 4; ++nt)
                bF[nt] = *(const short8*)&Lb[(wn * 64 + nt * 16 + ln) * 64 +
                                             ((kc ^ (ln & 7)) * 8)];
#pragma unroll
            for (int mt = 0; mt < 4; ++mt)
#pragma unroll
                for (int nt = 0; nt < 4; ++nt)
                    acc[mt][nt] = __builtin_amdgcn_mfma_f32_16x16x32_bf16(
                        aF[mt], bF[nt], acc[mt][nt], 0, 0, 0);
        }
    }

    if (out_bf16) {
        unsigned short* C = (unsigned short*)Cout;
#pragma unroll
        for (int mt = 0; mt < 4; ++mt)
#pragma unroll
            for (int nt = 0; nt < 4; ++nt)
#pragma unroll
                for (int r = 0; r < 4; ++r) {
                    int rr = m0 + wm * 64 + mt * 16 + quad * 4 + r;
                    int cc = n0 + wn * 64 + nt * 16 + ln;
                    unsigned short hv = f2bf(acc[mt][nt][r]);
                    C[(size_t)rr * N + cc] = hv;
                    if (VtOut != nullptr && cc >= DM + HD) {  // V cols: also transposed
                        int d = cc - (DM + HD);               // 0..63
                        int bb = rr >> 11, s = rr & 2047;
                        VtOut[((size_t)bb * HD + d) * SEQ + s] = hv;
                    }
                }
    } else {
        float* C = (float*)Cout;
#pragma unroll
        for (int mt = 0; mt < 4; ++mt)
#pragma unroll
            for (int nt = 0; nt < 4; ++nt)
#pragma unroll
                for (int r = 0; r < 4; ++r) {
                    int rr = m0 + wm * 64 + mt * 16 + quad * 4 + r;
                    int cc = n0 + wn * 64 + nt * 16 + ln;
                    C[(size_t)rr * N + cc] = acc[mt][nt][r];
                }
    }
}

// ---------------- flash attention (multi-query, causal) ----------------
// R7 design (best measured: 51.9 us). 64-key steps: block stages K(64x64) +
// Vt(64x64) into double-buffered LDS via global_load_lds ((row&7) xor chunk
// swizzle). 4 waves share the tiles; wave w owns q-tile jg*4+w: jg mask-free
// steps + 1 partial step. pbuf (per-wave 16x64, xor-swizzled, no pad) for
// the P C-layout -> A-layout round trip; LDS total 40960 B = 4 blocks/CU.
// Constant-max streaming softmax; P stored by truncation (>>16).
__global__ __launch_bounds__(256) void attn_kernel(
        const unsigned short* __restrict__ QKV,
        const unsigned short* __restrict__ Vt,
        unsigned short* __restrict__ Y) {
    __shared__ unsigned short ldsK[2][64 * 64];
    __shared__ unsigned short ldsV[2][64 * 64];
    __shared__ unsigned short pbuf[4][16 * 64];   // swizzled, per-wave

    int lane = threadIdx.x & 63, wave = threadIdx.x >> 6;
    int ln = lane & 15, quad = lane >> 4;
    int bid = blockIdx.x;
    int jg = 31 - (bid >> 5);             // heavy-first
    int bh = bid & 31;
    int h = bh & 15, b = bh >> 4;
    int q0 = (jg * 4 + wave) * 16;
    const size_t baseRow = (size_t)b * SEQ;
    const unsigned short* Vb = Vt + (size_t)b * HD * SEQ;

    int t = threadIdx.x;
    int trow = t >> 3, tcb = t & 7;
    int cbg = tcb ^ (trow & 7);
    const unsigned short* gK = QKV + (baseRow + trow) * LDQ + DM + cbg * 8;
    const unsigned short* gV = Vb + (size_t)trow * SEQ + cbg * 8;
    int dstoff = trow * 64 + tcb * 8;

    auto stageKV = [&](int s0n, int buf) {
#pragma unroll
        for (int rr = 0; rr < 2; ++rr) {
            gload16(gK + (size_t)(s0n + 32 * rr) * LDQ, &ldsK[buf][dstoff + rr * 2048]);
            gload16(gV + (size_t)32 * rr * SEQ + s0n,   &ldsV[buf][dstoff + rr * 2048]);
        }
    };

    // Q fragments (A-layout)
    short8 aQ0, aQ1;
    {
        const unsigned short* qp = QKV + (baseRow + q0 + ln) * LDQ + h * HD + quad * 8;
        aQ0 = *(const short8*)(qp);
        aQ1 = *(const short8*)(qp + 32);
    }

    float lsum[4] = {0.f, 0.f, 0.f, 0.f};
    f32x4 o[4];
    for (int nt = 0; nt < 4; ++nt) o[nt] = f32x4{0, 0, 0, 0};

    const float c_exp = 0.1803368802f;    // 0.125 * log2(e)
    unsigned short* pb = &pbuf[wave][0];

    auto computeStep = [&](int s0, int buf, bool partial) {
        const unsigned short* Kb = ldsK[buf];
        const unsigned short* Vf = ldsV[buf];
#pragma unroll
        for (int c = 0; c < 4; ++c) {
            int kbase = s0 + c * 16;
            if (partial && kbase > q0 + 15) {   // fully masked tile: zero P
#pragma unroll
                for (int r = 0; r < 4; ++r) {
                    int row = quad * 4 + r;
                    pb[row * 64 + (((c * 2 + (ln >> 3)) ^ (row & 7)) * 8) + (ln & 7)] = 0;
                }
                continue;
            }
            short8 k0f = *(const short8*)&Kb[(c * 16 + ln) * 64 + ((quad ^ (ln & 7)) * 8)];
            short8 k1f = *(const short8*)&Kb[(c * 16 + ln) * 64 + (((4 + quad) ^ (ln & 7)) * 8)];
            f32x4 s = {0, 0, 0, 0};
            s = __builtin_amdgcn_mfma_f32_16x16x32_bf16(aQ0, k0f, s, 0, 0, 0);
            s = __builtin_amdgcn_mfma_f32_16x16x32_bf16(aQ1, k1f, s, 0, 0, 0);
            bool diag = partial && (kbase + 15 > q0);
#pragma unroll
            for (int r = 0; r < 4; ++r) {
                float e = __builtin_exp2f(s[r] * c_exp);
                if (diag && (kbase + ln > q0 + quad * 4 + r)) e = 0.f;  // causal
                lsum[r] += e;
                int row = quad * 4 + r;
                pb[row * 64 + (((c * 2 + (ln >> 3)) ^ (row & 7)) * 8) + (ln & 7)] =
                    (unsigned short)(__float_as_uint(e) >> 16);        // bf16 trunc
            }
        }
        short8 aP0 = *(const short8*)&pb[ln * 64 + ((quad ^ (ln & 7)) * 8)];
        short8 aP1 = *(const short8*)&pb[ln * 64 + (((4 + quad) ^ (ln & 7)) * 8)];
#pragma unroll
        for (int nt = 0; nt < 4; ++nt) {
            short8 v0 = *(const short8*)&Vf[(nt * 16 + ln) * 64 + ((quad ^ (ln & 7)) * 8)];
            short8 v1 = *(const short8*)&Vf[(nt * 16 + ln) * 64 + (((4 + quad) ^ (ln & 7)) * 8)];
            o[nt] = __builtin_amdgcn_mfma_f32_16x16x32_bf16(aP0, v0, o[nt], 0, 0, 0);
            o[nt] = __builtin_amdgcn_mfma_f32_16x16x32_bf16(aP1, v1, o[nt], 0, 0, 0);
        }
    };

    stageKV(0, 0);
    for (int it = 0; it < jg; ++it) {          // full steps, mask-free
        __syncthreads();
        stageKV((it + 1) * 64, (it + 1) & 1);
        computeStep(it * 64, it & 1, false);
    }
    __syncthreads();
    computeStep(jg * 64, jg & 1, true);        // the one partial step

    // epilogue: reduce l across the 16 lanes of each quad, then Y = O / l
    for (int off = 1; off < 16; off <<= 1)
#pragma unroll
        for (int r = 0; r < 4; ++r) lsum[r] += __shfl_xor(lsum[r], off);
#pragma unroll
    for (int r = 0; r < 4; ++r) {
        float inv = 1.0f / lsum[r];
        int t_idx = q0 + quad * 4 + r;
        unsigned short* yp = Y + (baseRow + t_idx) * DM + h * HD + ln;
        for (int nt = 0; nt < 4; ++nt)
            yp[nt * 16] = f2bf(o[nt][r] * inv);
    }
}

extern "C" void kernel_launch(void* const* d_in, const int* in_sizes, int n_in,
                              void* d_out, int out_size, void* d_ws, size_t ws_size,
                              hipStream_t stream) {
    const float* x  = (const float*)d_in[0];
    const float* Wq = (const float*)d_in[1];
    const float* Wk = (const float*)d_in[2];
    const float* Wv = (const float*)d_in[3];
    const float* Wo = (const float*)d_in[4];
    float* out = (float*)d_out;

    char* ws = (char*)d_ws;
    // workspace (22.8 MB): slot0 is xb until qkv-gemm completes, then y.
    unsigned short* xb  = (unsigned short*)(ws);                // 4096x1024 bf16 (8 MB)
    unsigned short* y   = (unsigned short*)(ws);                // alias: attn out
    unsigned short* wtq = (unsigned short*)(ws + 8388608);      // 1152x1024 bf16
    unsigned short* wot = (unsigned short*)(ws + 10747904);     // 1024x1024 bf16
    unsigned short* qkv = (unsigned short*)(ws + 12845056);     // 4096x1152 bf16
    unsigned short* Vt  = (unsigned short*)(ws + 22282240);     // 2x64x2048 bf16 (0.5 MB)

    const int BT = BATCH * SEQ;  // 4096 rows

    hipLaunchKernelGGL(cast_x_kernel, dim3(BT * DM / 4 / 256), dim3(256), 0, stream,
                       x, xb, BT * DM);
    hipLaunchKernelGGL(prep_w_kernel, dim3(DM / 32, DM / 32, 4), dim3(256), 0, stream,
                       Wq, Wk, Wv, Wo, wtq, wot);

    // QKV = x @ [Wq|Wk|Wv] -> bf16; V cols also written transposed to Vt
    // 288 blocks = 8 XCDs x 4 row-strips x 9 cols (XCD-aware remap inside)
    hipLaunchKernelGGL(gemm128_kernel, dim3((LDQ / 128) * (BT / 128)), dim3(256), 0, stream,
                       xb, wtq, (void*)qkv, Vt, BT, LDQ, DM, 1, LDQ / 128);

    // flash attention (64-key dbuf steps) -> y bf16 (overwrites xb, now dead)
    hipLaunchKernelGGL(attn_kernel, dim3(32 * 32), dim3(256), 0, stream,
                       qkv, Vt, y);

    // out = y @ Wo -> fp32; 256 blocks = 8 XCDs x 4 row-strips x 8 cols
    hipLaunchKernelGGL(gemm128_kernel, dim3((DM / 128) * (BT / 128)), dim3(256), 0, stream,
                       y, wot, (void*)out, nullptr, BT, DM, DM, 0, DM / 128);
}

// Round 2
// 169.171 us; speedup vs baseline: 1.0228x; 1.0228x over previous
//
#include <hip/hip_runtime.h>
#include <hip/hip_bf16.h>
#include <stdint.h>

typedef short short8 __attribute__((ext_vector_type(8)));
typedef float f32x4 __attribute__((ext_vector_type(4)));

// Problem constants
constexpr int SEQ   = 2048;   // T
constexpr int DM    = 1024;   // model dim
constexpr int NHEAD = 16;
constexpr int HD    = 64;     // head dim
constexpr int LDQ   = 1152;   // QKV row stride: 1024 Q | 64 K | 64 V
constexpr int BATCH = 2;

__device__ __forceinline__ unsigned short f2bf(float f) {
    union { float f; uint32_t u; } v; v.f = f;
    uint32_t u = v.u;
    uint32_t r = (u + 0x7fffu + ((u >> 16) & 1u)) >> 16;
    return (unsigned short)r;
}

// async global->LDS, 16B per lane. LDS dest = wave-uniform base + lane*16.
typedef __attribute__((address_space(1))) const void gvoid_t;
typedef __attribute__((address_space(3))) void lvoid_t;
__device__ __forceinline__ void gload16(const void* g, void* l) {
    __builtin_amdgcn_global_load_lds((gvoid_t*)g, (lvoid_t*)l, 16, 0, 0);
}

// ---------------- cast x (fp32 -> bf16), vectorized ----------------
__global__ __launch_bounds__(256) void cast_x_kernel(
        const float* __restrict__ x, unsigned short* __restrict__ xb, int n) {
    int i = (blockIdx.x * 256 + threadIdx.x) * 4;
    if (i >= n) return;
    const float4 v = *(const float4*)(x + i);
    ushort4 o;
    o.x = f2bf(v.x); o.y = f2bf(v.y); o.z = f2bf(v.z); o.w = f2bf(v.w);
    *(ushort4*)(xb + i) = o;
}

// ---- fused weight prep: cast+transpose Wq,Wk,Wv,Wo in one launch ----
__global__ __launch_bounds__(256) void prep_w_kernel(
        const float* __restrict__ Wq, const float* __restrict__ Wk,
        const float* __restrict__ Wv, const float* __restrict__ Wo,
        unsigned short* __restrict__ wtq, unsigned short* __restrict__ wot) {
    __shared__ unsigned short tile[32][33];
    int z = blockIdx.z;
    const float* W; unsigned short* Wt; int C;
    if (z == 0)      { W = Wq; Wt = wtq;                              C = DM; }
    else if (z == 1) { W = Wk; Wt = wtq + (size_t)DM * DM;            C = HD; }
    else if (z == 2) { W = Wv; Wt = wtq + (size_t)(DM + HD) * DM;     C = HD; }
    else             { W = Wo; Wt = wot;                              C = DM; }
    int c0 = blockIdx.x * 32, r0 = blockIdx.y * 32;
    if (c0 >= C) return;
    int tx = threadIdx.x & 31, ty = threadIdx.x >> 5;  // ty 0..7
    for (int i = ty; i < 32; i += 8)
        tile[i][tx] = f2bf(W[(size_t)(r0 + i) * C + (c0 + tx)]);
    __syncthreads();
    for (int i = ty; i < 32; i += 8)
        Wt[(size_t)(c0 + i) * DM + (r0 + tx)] = tile[tx][i];
}

// --------- GEMM: C[M,N] = A[M,K](bf16) @ Bt[N,K]^T(bf16), 128x64 tile ---------
// BK=64, double-buffered LDS (48 KB), global_load_lds width-16 staging with
// (row&7) xor chunk swizzle pre-applied on the GLOBAL source (linear LDS dest)
// and the matching xor on the ds_read side. 4 waves in a 2x2 grid, each owns
// a 64x32 quadrant: acc[4][2], 16 MFMA : 12 ds_read_b128 per wave per K-step.
// Tile chosen for GRID SIZE, not per-block ratio: QKV = 32x18 = 576 blocks
// (2.25 blocks/CU), out-proj = 32x16 = 512 (2.0/CU) -- R1 showed 128x128's
// 288/256-block grids starve the CUs (1 wave/SIMD, fully exposed latency).
// Bijective XCD-aware remap: rows_per_xcd = grid/(8*ncols) integral
// (QKV: 576/(8*18)=4, out: 512/(8*16)=4).
__global__ __launch_bounds__(256) void gemm_kernel(
        const unsigned short* __restrict__ A,
        const unsigned short* __restrict__ Bt,
        void* __restrict__ Cout,
        unsigned short* __restrict__ VtOut,
        int M, int N, int K, int out_bf16, int ncols) {
    __shared__ unsigned short ldsA[2][128 * 64];
    __shared__ unsigned short ldsB[2][64 * 64];
    int lane = threadIdx.x & 63, wave = threadIdx.x >> 6;
    int ln = lane & 15, quad = lane >> 4;
    int wm = wave >> 1, wn = wave & 1;

    // XCD-aware block remap (bijective: gridDim.x % 8 == 0)
    int g = blockIdx.x;
    int xcd = g & 7, idx = g >> 3;
    int rows_per_xcd = (int)(gridDim.x >> 3) / ncols;
    int row = xcd * rows_per_xcd + idx / ncols;
    int col = idx % ncols;
    int m0 = row * 128, n0 = col * 64;

    int t = threadIdx.x;
    int trow = t >> 3, tcb = t & 7;          // 32 rows x 8 chunks per batch
    int gcb = tcb ^ (trow & 7);              // pre-swizzled global chunk
    const unsigned short* gA = A + (size_t)(m0 + trow) * K + gcb * 8;
    const unsigned short* gB = Bt + (size_t)(n0 + trow) * K + gcb * 8;
    int dst = t * 8;                          // shorts; batch rr adds 2048

    auto stage = [&](int k0, int buf) {
#pragma unroll
        for (int rr = 0; rr < 4; ++rr)
            gload16(gA + (size_t)rr * 32 * K + k0, &ldsA[buf][dst + rr * 2048]);
#pragma unroll
        for (int rr = 0; rr < 2; ++rr)
            gload16(gB + (size_t)rr * 32 * K + k0, &ldsB[buf][dst + rr * 2048]);
    };

    f32x4 acc[4][2];
#pragma unroll
    for (int i = 0; i < 4; ++i)
#pragma unroll
        for (int j = 0; j < 2; ++j) acc[i][j] = f32x4{0, 0, 0, 0};

    stage(0, 0);
    int niter = K >> 6;
    for (int it = 0; it < niter; ++it) {
        __syncthreads();                       // drains vmcnt: buf(it&1) ready
        if (it + 1 < niter) stage((it + 1) << 6, (it + 1) & 1);
        const unsigned short* La = ldsA[it & 1];
        const unsigned short* Lb = ldsB[it & 1];
#pragma unroll
        for (int hh = 0; hh < 2; ++hh) {
            int kc = hh * 4 + quad;
            short8 aF[4], bF[2];
#pragma unroll
            for (int mt = 0; mt < 4; ++mt)
                aF[mt] = *(const short8*)&La[(wm * 64 + mt * 16 + ln) * 64 +
                                             ((kc ^ (ln & 7)) * 8)];
#pragma unroll
            for (int nt = 0; nt < 2; ++nt)
                bF[nt] = *(const short8*)&Lb[(wn * 32 + nt * 16 + ln) * 64 +
                                             ((kc ^ (ln & 7)) * 8)];
#pragma unroll
            for (int mt = 0; mt < 4; ++mt)
#pragma unroll
                for (int nt = 0; nt < 2; ++nt)
                    acc[mt][nt] = __builtin_amdgcn_mfma_f32_16x16x32_bf16(
                        aF[mt], bF[nt], acc[mt][nt], 0, 0, 0);
        }
    }

    if (out_bf16) {
        unsigned short* C = (unsigned short*)Cout;
#pragma unroll
        for (int mt = 0; mt < 4; ++mt)
#pragma unroll
            for (int nt = 0; nt < 2; ++nt)
#pragma unroll
                for (int r = 0; r < 4; ++r) {
                    int rr = m0 + wm * 64 + mt * 16 + quad * 4 + r;
                    int cc = n0 + wn * 32 + nt * 16 + ln;
                    unsigned short hv = f2bf(acc[mt][nt][r]);
                    C[(size_t)rr * N + cc] = hv;
                    if (VtOut != nullptr && cc >= DM + HD) {  // V cols: also transposed
                        int d = cc - (DM + HD);               // 0..63
                        int bb = rr >> 11, s = rr & 2047;
                        VtOut[((size_t)bb * HD + d) * SEQ + s] = hv;
                    }
                }
    } else {
        float* C = (float*)Cout;
#pragma unroll
        for (int mt = 0; mt < 4; ++mt)
#pragma unroll
            for (int nt = 0; nt < 2; ++nt)
#pragma unroll
                for (int r = 0; r < 4; ++r) {
                    int rr = m0 + wm * 64 + mt * 16 + quad * 4 + r;
                    int cc = n0 + wn * 32 + nt * 16 + ln;
                    C[(size_t)rr * N + cc] = acc[mt][nt][r];
                }
    }
}

// ---------------- flash attention (multi-query, causal) ----------------
// R2: 8-wave (512-thread) blocks. Same per-wave work as the R7 4-wave design
// (wave w owns q-tile jg*8+w, 16 rows), but 8 q-tiles share one staged K/V
// stream: grid 512 blocks, 2 blocks/CU x 8 waves = ~50% occupancy (2x R1's
// 25.7%), and K/V staging traffic halves. 64-key dbuf steps via
// global_load_lds ((row&7) xor chunk swizzle); per-wave pbuf (16x64,
// xor-swizzled) for the P C-layout -> A-layout round trip. LDS 48 KB.
// Wave w: nfull = 2*jg + (w>>2) mask-free steps, partial at it==nfull,
// barrier-only afterwards. Constant-max streaming softmax; P by truncation.
__global__ __launch_bounds__(512) void attn_kernel(
        const unsigned short* __restrict__ QKV,
        const unsigned short* __restrict__ Vt,
        unsigned short* __restrict__ Y) {
    __shared__ unsigned short ldsK[2][64 * 64];
    __shared__ unsigned short ldsV[2][64 * 64];
    __shared__ unsigned short pbuf[8][16 * 64];   // swizzled, per-wave

    int lane = threadIdx.x & 63, wave = threadIdx.x >> 6;  // wave 0..7
    int ln = lane & 15, quad = lane >> 4;
    int bid = blockIdx.x;
    int jg = 15 - (bid >> 5);             // heavy-first, jg 0..15
    int bh = bid & 31;
    int h = bh & 15, b = bh >> 4;
    int q0 = (jg * 8 + wave) * 16;
    const size_t baseRow = (size_t)b * SEQ;
    const unsigned short* Vb = Vt + (size_t)b * HD * SEQ;

    int t = threadIdx.x;
    int trow = t >> 3, tcb = t & 7;       // 64 rows x 8 chunks (512 threads)
    int cbg = tcb ^ (trow & 7);
    const unsigned short* gK = QKV + (baseRow + trow) * LDQ + DM + cbg * 8;
    const unsigned short* gV = Vb + (size_t)trow * SEQ + cbg * 8;
    int dstoff = t * 8;

    auto stageKV = [&](int s0n, int buf) {
        gload16(gK + (size_t)s0n * LDQ, &ldsK[buf][dstoff]);
        gload16(gV + s0n,               &ldsV[buf][dstoff]);
    };

    // Q fragments (A-layout)
    short8 aQ0, aQ1;
    {
        const unsigned short* qp = QKV + (baseRow + q0 + ln) * LDQ + h * HD + quad * 8;
        aQ0 = *(const short8*)(qp);
        aQ1 = *(const short8*)(qp + 32);
    }

    float lsum[4] = {0.f, 0.f, 0.f, 0.f};
    f32x4 o[4];
    for (int nt = 0; nt < 4; ++nt) o[nt] = f32x4{0, 0, 0, 0};

    const float c_exp = 0.1803368802f;    // 0.125 * log2(e)
    unsigned short* pb = &pbuf[wave][0];

    auto computeStep = [&](int s0, int buf, bool partial) {
        const unsigned short* Kb = ldsK[buf];
        const unsigned short* Vf = ldsV[buf];
#pragma unroll
        for (int c = 0; c < 4; ++c) {
            int kbase = s0 + c * 16;
            if (partial && kbase > q0 + 15) {   // fully masked tile: zero P
#pragma unroll
                for (int r = 0; r < 4; ++r) {
                    int row = quad * 4 + r;
                    pb[row * 64 + (((c * 2 + (ln >> 3)) ^ (row & 7)) * 8) + (ln & 7)] = 0;
                }
                continue;
            }
            short8 k0f = *(const short8*)&Kb[(c * 16 + ln) * 64 + ((quad ^ (ln & 7)) * 8)];
            short8 k1f = *(const short8*)&Kb[(c * 16 + ln) * 64 + (((4 + quad) ^ (ln & 7)) * 8)];
            f32x4 s = {0, 0, 0, 0};
            s = __builtin_amdgcn_mfma_f32_16x16x32_bf16(aQ0, k0f, s, 0, 0, 0);
            s = __builtin_amdgcn_mfma_f32_16x16x32_bf16(aQ1, k1f, s, 0, 0, 0);
            bool diag = partial && (kbase + 15 > q0);
#pragma unroll
            for (int r = 0; r < 4; ++r) {
                float e = __builtin_exp2f(s[r] * c_exp);
                if (diag && (kbase + ln > q0 + quad * 4 + r)) e = 0.f;  // causal
                lsum[r] += e;
                int row = quad * 4 + r;
                pb[row * 64 + (((c * 2 + (ln >> 3)) ^ (row & 7)) * 8) + (ln & 7)] =
                    (unsigned short)(__float_as_uint(e) >> 16);        // bf16 trunc
            }
        }
        short8 aP0 = *(const short8*)&pb[ln * 64 + ((quad ^ (ln & 7)) * 8)];
        short8 aP1 = *(const short8*)&pb[ln * 64 + (((4 + quad) ^ (ln & 7)) * 8)];
#pragma unroll
        for (int nt = 0; nt < 4; ++nt) {
            short8 v0 = *(const short8*)&Vf[(nt * 16 + ln) * 64 + ((quad ^ (ln & 7)) * 8)];
            short8 v1 = *(const short8*)&Vf[(nt * 16 + ln) * 64 + (((4 + quad) ^ (ln & 7)) * 8)];
            o[nt] = __builtin_amdgcn_mfma_f32_16x16x32_bf16(aP0, v0, o[nt], 0, 0, 0);
            o[nt] = __builtin_amdgcn_mfma_f32_16x16x32_bf16(aP1, v1, o[nt], 0, 0, 0);
        }
    };

    int nfull  = 2 * jg + (wave >> 2);    // mask-free steps for this wave
    int nsteps = 2 * jg + 2;              // staged steps for the block
    stageKV(0, 0);
    for (int it = 0; it < nsteps; ++it) {
        __syncthreads();
        if (it + 1 < nsteps) stageKV((it + 1) * 64, (it + 1) & 1);
        if (it < nfull)       computeStep(it * 64, it & 1, false);
        else if (it == nfull) computeStep(it * 64, it & 1, true);
        // it > nfull: fully masked for this wave -- barrier only
    }

    // epilogue: reduce l across the 16 lanes of each quad, then Y = O / l
    for (int off = 1; off < 16; off <<= 1)
#pragma unroll
        for (int r = 0; r < 4; ++r) lsum[r] += __shfl_xor(lsum[r], off);
#pragma unroll
    for (int r = 0; r < 4; ++r) {
        float inv = 1.0f / lsum[r];
        int t_idx = q0 + quad * 4 + r;
        unsigned short* yp = Y + (baseRow + t_idx) * DM + h * HD + ln;
        for (int nt = 0; nt < 4; ++nt)
            yp[nt * 16] = f2bf(o[nt][r] * inv);
    }
}

extern "C" void kernel_launch(void* const* d_in, const int* in_sizes, int n_in,
                              void* d_out, int out_size, void* d_ws, size_t ws_size,
                              hipStream_t stream) {
    const float* x  = (const float*)d_in[0];
    const float* Wq = (const float*)d_in[1];
    const float* Wk = (const float*)d_in[2];
    const float* Wv = (const float*)d_in[3];
    const float* Wo = (const float*)d_in[4];
    float* out = (float*)d_out;

    char* ws = (char*)d_ws;
    // workspace (22.8 MB): slot0 is xb until qkv-gemm completes, then y.
    unsigned short* xb  = (unsigned short*)(ws);                // 4096x1024 bf16 (8 MB)
    unsigned short* y   = (unsigned short*)(ws);                // alias: attn out
    unsigned short* wtq = (unsigned short*)(ws + 8388608);      // 1152x1024 bf16
    unsigned short* wot = (unsigned short*)(ws + 10747904);     // 1024x1024 bf16
    unsigned short* qkv = (unsigned short*)(ws + 12845056);     // 4096x1152 bf16
    unsigned short* Vt  = (unsigned short*)(ws + 22282240);     // 2x64x2048 bf16 (0.5 MB)

    const int BT = BATCH * SEQ;  // 4096 rows

    hipLaunchKernelGGL(cast_x_kernel, dim3(BT * DM / 4 / 256), dim3(256), 0, stream,
                       x, xb, BT * DM);
    hipLaunchKernelGGL(prep_w_kernel, dim3(DM / 32, DM / 32, 4), dim3(256), 0, stream,
                       Wq, Wk, Wv, Wo, wtq, wot);

    // QKV = x @ [Wq|Wk|Wv] -> bf16; V cols also written transposed to Vt
    // 576 blocks = 8 XCDs x 4 row-strips x 18 cols (XCD-aware remap inside)
    hipLaunchKernelGGL(gemm_kernel, dim3((BT / 128) * (LDQ / 64)), dim3(256), 0, stream,
                       xb, wtq, (void*)qkv, Vt, BT, LDQ, DM, 1, LDQ / 64);

    // flash attention (8-wave, 64-key dbuf steps) -> y bf16 (overwrites xb)
    hipLaunchKernelGGL(attn_kernel, dim3(16 * 32), dim3(512), 0, stream,
                       qkv, Vt, y);

    // out = y @ Wo -> fp32; 512 blocks = 8 XCDs x 4 row-strips x 16 cols
    hipLaunchKernelGGL(gemm_kernel, dim3((BT / 128) * (DM / 64)), dim3(256), 0, stream,
                       y, wot, (void*)out, nullptr, BT, DM, DM, 0, DM / 64);
}